// Round 4
// baseline (8079.220 us; speedup 1.0000x reference)
//
#include <hip/hip_runtime.h>
#include <math.h>

#define AGENT __HIP_MEMORY_SCOPE_AGENT
typedef unsigned long long u64;

__device__ __forceinline__ float sigf(float x) { return 1.f / (1.f + __expf(-x)); }
__device__ __forceinline__ float tanh_fast(float x) { return 1.f - 2.f / (__expf(2.f * x) + 1.f); }
__device__ __forceinline__ float lrelu(float x) { return x > 0.f ? x : 0.01f * x; }
__device__ __forceinline__ u64 aload64(const u64* p) {
    return __hip_atomic_load(p, __ATOMIC_RELAXED, AGENT);
}
__device__ __forceinline__ void astore64(u64* p, u64 v) {
    __hip_atomic_store(p, v, __ATOMIC_RELAXED, AGENT);
}

// ---------------- generic fp32 GEMM: C[m][n] = sum_k A[m][k]*B[n][k] + bias ----
template <bool LRELU>
__global__ __launch_bounds__(256) void gemm_bias(
    const float* __restrict__ A, const float* __restrict__ B,
    const float* __restrict__ bias1, const float* __restrict__ bias2,
    float* __restrict__ C, int M, int N, int K)
{
    __shared__ float As[16][68];
    __shared__ float Bs[16][68];
    const int tid = threadIdx.x;
    const int m0 = blockIdx.y * 64, n0 = blockIdx.x * 64;
    const int tm = tid >> 4, tn = tid & 15;
    const int lr = tid >> 2;
    const int lk = (tid & 3) * 4;
    float acc[4][4] = {};
    for (int k0 = 0; k0 < K; k0 += 16) {
        float4 av = make_float4(0.f, 0.f, 0.f, 0.f);
        if (m0 + lr < M) av = *(const float4*)&A[(size_t)(m0 + lr) * K + k0 + lk];
        As[lk + 0][lr] = av.x; As[lk + 1][lr] = av.y;
        As[lk + 2][lr] = av.z; As[lk + 3][lr] = av.w;
        float4 bv = make_float4(0.f, 0.f, 0.f, 0.f);
        if (n0 + lr < N) bv = *(const float4*)&B[(size_t)(n0 + lr) * K + k0 + lk];
        Bs[lk + 0][lr] = bv.x; Bs[lk + 1][lr] = bv.y;
        Bs[lk + 2][lr] = bv.z; Bs[lk + 3][lr] = bv.w;
        __syncthreads();
#pragma unroll
        for (int kk = 0; kk < 16; kk++) {
            float a[4], b[4];
#pragma unroll
            for (int i = 0; i < 4; i++) a[i] = As[kk][tm * 4 + i];
#pragma unroll
            for (int j = 0; j < 4; j++) b[j] = Bs[kk][tn * 4 + j];
#pragma unroll
            for (int i = 0; i < 4; i++)
#pragma unroll
                for (int j = 0; j < 4; j++) acc[i][j] += a[i] * b[j];
        }
        __syncthreads();
    }
#pragma unroll
    for (int i = 0; i < 4; i++) {
#pragma unroll
        for (int j = 0; j < 4; j++) {
            int mm = m0 + tm * 4 + i, nn = n0 + tn * 4 + j;
            if (mm < M && nn < N) {
                float v = acc[i][j];
                if (bias1) v += bias1[nn];
                if (bias2) v += bias2[nn];
                if (LRELU) v = lrelu(v);
                C[(size_t)mm * N + nn] = v;
            }
        }
    }
}

// pad helpers: X-segments are 32 wide (+4 floats per seg), H-segments 16 wide (+4)
#define XPAD(i) ((i) + 4 * ((i) >> 5))
#define HPAD(i) ((i) + 4 * ((i) >> 4))

// ---------------- persistent pipelined LSTM1+LSTM2 scan ------------------------
// Tagged-data sync (unchanged). Compute restructured: 2 gate-rows per thread,
// 16 K-segments, float4 LDS reads with pad-swizzle, 2 barriers/step, one-wave
// reduce, fast tanh, gx prefetch on lanes 224..255.
__global__ __launch_bounds__(256) void lstm_pipe(
    const float* __restrict__ gx1, const float* __restrict__ Whh1,
    const float* __restrict__ Wih2, const float* __restrict__ Whh2,
    const float* __restrict__ bih2, const float* __restrict__ bhh2,
    u64* __restrict__ h1pub, u64* __restrict__ h2pub,
    float* __restrict__ h2seq)
{
    const int wg = blockIdx.x, tid = threadIdx.x;
    const int s = tid >> 4;        // K-segment 0..15
    const int rp = tid & 15;       // row-pair 0..15
    const int row0 = 2 * rp, row1 = row0 + 1;
    __shared__ float xl[16 * 36];          // 512 + pad
    __shared__ float hl[16 * 20];          // 256 + pad
    __shared__ float partb[16 * 34];       // [seg][row(+pad)]
    __shared__ float gxl[2][32];

    if (wg < 64) {
        // ---------------- LSTM1: H=512, owns h[jb..jb+8) ----------------
        const int jb = wg * 8;
        const int g0 = (row0 >> 3) * 512 + jb + (row0 & 7);
        const int g1 = (row1 >> 3) * 512 + jb + (row1 & 7);
        float w0[32], w1[32];
        {
            const float* W0 = Whh1 + (size_t)g0 * 512 + 32 * s;
            const float* W1 = Whh1 + (size_t)g1 * 512 + 32 * s;
#pragma unroll
            for (int q = 0; q < 8; q++) {
                float4 a = *(const float4*)&W0[4 * q];
                float4 b = *(const float4*)&W1[4 * q];
                w0[4 * q] = a.x; w0[4 * q + 1] = a.y; w0[4 * q + 2] = a.z; w0[4 * q + 3] = a.w;
                w1[4 * q] = b.x; w1[4 * q + 1] = b.y; w1[4 * q + 2] = b.z; w1[4 * q + 3] = b.w;
            }
        }
        float cstate = 0.f;  // lanes 0..7 of wave 0

        for (int t = 0; t < 4096; ++t) {
            // gx prefetch on lanes 224..255 (off the reduce lanes)
            float gxv = 0.f;
            if (tid >= 224) {
                int gi = tid - 224;
                gxv = gx1[(size_t)t * 2048 + (gi >> 3) * 512 + jb + (gi & 7)];
            }
            // poll h(t-1): 2 tagged words per thread
            float fa = 0.f, fb = 0.f;
            if (t > 0) {
                const u64* base = h1pub + (size_t)(t - 1) * 512;
                const u64 want = (u64)t;
                u64 a = aload64(base + 2 * tid);
                u64 b = aload64(base + 2 * tid + 1);
                while (!__all(((a >> 32) == want) & ((b >> 32) == want))) {
                    if ((a >> 32) != want) a = aload64(base + 2 * tid);
                    if ((b >> 32) != want) b = aload64(base + 2 * tid + 1);
                }
                fa = __uint_as_float((unsigned)a);
                fb = __uint_as_float((unsigned)b);
            }
            if (tid >= 224) gxl[t & 1][tid - 224] = gxv;
            *(float2*)&xl[XPAD(2 * tid)] = make_float2(fa, fb);
            __syncthreads();  // B1: xl ready
            float acc0 = 0.f, acc1 = 0.f;
#pragma unroll
            for (int q4 = 0; q4 < 8; ++q4) {
                float4 xv = *(const float4*)&xl[36 * s + 4 * q4];
                acc0 += w0[4 * q4] * xv.x + w0[4 * q4 + 1] * xv.y
                      + w0[4 * q4 + 2] * xv.z + w0[4 * q4 + 3] * xv.w;
                acc1 += w1[4 * q4] * xv.x + w1[4 * q4 + 1] * xv.y
                      + w1[4 * q4 + 2] * xv.z + w1[4 * q4 + 3] * xv.w;
            }
            *(float2*)&partb[s * 34 + 2 * rp] = make_float2(acc0, acc1);
            __syncthreads();  // B2: partials ready
            if (tid < 32) {
                float sum = gxl[t & 1][tid];
#pragma unroll
                for (int ss = 0; ss < 16; ++ss) sum += partb[ss * 34 + tid];
                float act = ((tid >> 3) == 2) ? tanh_fast(sum) : sigf(sum);
                const int e = tid & 7;
                float vi = __shfl(act, e, 64);
                float vf = __shfl(act, e + 8, 64);
                float vg = __shfl(act, e + 16, 64);
                float vo = __shfl(act, e + 24, 64);
                if (tid < 8) {
                    float c = vf * cstate + vi * vg;
                    cstate = c;
                    float h = vo * tanh_fast(c);
                    astore64(h1pub + (size_t)t * 512 + jb + tid,
                             ((u64)(t + 1) << 32) | (u64)__float_as_uint(h));
                }
            }
        }
    } else {
        // ---------------- LSTM2: H=256, pipelined 1 step behind ----------------
        const int k = wg - 64, jb = k * 8;
        const int g0 = (row0 >> 3) * 256 + jb + (row0 & 7);
        const int g1 = (row1 >> 3) * 256 + jb + (row1 & 7);
        float wx0[32], wx1[32], wh0[16], wh1[16];
        {
            const float* X0 = Wih2 + (size_t)g0 * 512 + 32 * s;
            const float* X1 = Wih2 + (size_t)g1 * 512 + 32 * s;
#pragma unroll
            for (int q = 0; q < 8; q++) {
                float4 a = *(const float4*)&X0[4 * q];
                float4 b = *(const float4*)&X1[4 * q];
                wx0[4 * q] = a.x; wx0[4 * q + 1] = a.y; wx0[4 * q + 2] = a.z; wx0[4 * q + 3] = a.w;
                wx1[4 * q] = b.x; wx1[4 * q + 1] = b.y; wx1[4 * q + 2] = b.z; wx1[4 * q + 3] = b.w;
            }
            const float* H0 = Whh2 + (size_t)g0 * 256 + 16 * s;
            const float* H1 = Whh2 + (size_t)g1 * 256 + 16 * s;
#pragma unroll
            for (int q = 0; q < 4; q++) {
                float4 a = *(const float4*)&H0[4 * q];
                float4 b = *(const float4*)&H1[4 * q];
                wh0[4 * q] = a.x; wh0[4 * q + 1] = a.y; wh0[4 * q + 2] = a.z; wh0[4 * q + 3] = a.w;
                wh1[4 * q] = b.x; wh1[4 * q + 1] = b.y; wh1[4 * q + 2] = b.z; wh1[4 * q + 3] = b.w;
            }
        }
        float bs = 0.f;
        if (tid < 32) {
            int row = (tid >> 3) * 256 + jb + (tid & 7);
            bs = bih2[row] + bhh2[row];
        }
        float cstate = 0.f;

        for (int t = 0; t < 4096; ++t) {
            {
                const u64* b1 = h1pub + (size_t)t * 512;
                const u64* b2 = h2pub + (size_t)(t - 1) * 256;
                const u64 want1 = (u64)(t + 1);
                const u64 want2 = (u64)t;
                u64 a = aload64(b1 + 2 * tid);
                u64 b = aload64(b1 + 2 * tid + 1);
                u64 c = (t > 0) ? aload64(b2 + tid) : (want2 << 32);
                while (!__all(((a >> 32) == want1) & ((b >> 32) == want1) &
                              ((c >> 32) == want2))) {
                    if ((a >> 32) != want1) a = aload64(b1 + 2 * tid);
                    if ((b >> 32) != want1) b = aload64(b1 + 2 * tid + 1);
                    if ((c >> 32) != want2) c = aload64(b2 + tid);
                }
                *(float2*)&xl[XPAD(2 * tid)] =
                    make_float2(lrelu(__uint_as_float((unsigned)a)),
                                lrelu(__uint_as_float((unsigned)b)));
                hl[HPAD(tid)] = (t > 0) ? __uint_as_float((unsigned)c) : 0.f;
            }
            __syncthreads();  // B1
            float acc0 = 0.f, acc1 = 0.f;
#pragma unroll
            for (int q4 = 0; q4 < 8; ++q4) {
                float4 xv = *(const float4*)&xl[36 * s + 4 * q4];
                acc0 += wx0[4 * q4] * xv.x + wx0[4 * q4 + 1] * xv.y
                      + wx0[4 * q4 + 2] * xv.z + wx0[4 * q4 + 3] * xv.w;
                acc1 += wx1[4 * q4] * xv.x + wx1[4 * q4 + 1] * xv.y
                      + wx1[4 * q4 + 2] * xv.z + wx1[4 * q4 + 3] * xv.w;
            }
#pragma unroll
            for (int q4 = 0; q4 < 4; ++q4) {
                float4 hv = *(const float4*)&hl[20 * s + 4 * q4];
                acc0 += wh0[4 * q4] * hv.x + wh0[4 * q4 + 1] * hv.y
                      + wh0[4 * q4 + 2] * hv.z + wh0[4 * q4 + 3] * hv.w;
                acc1 += wh1[4 * q4] * hv.x + wh1[4 * q4 + 1] * hv.y
                      + wh1[4 * q4 + 2] * hv.z + wh1[4 * q4 + 3] * hv.w;
            }
            *(float2*)&partb[s * 34 + 2 * rp] = make_float2(acc0, acc1);
            __syncthreads();  // B2
            if (tid < 32) {
                float sum = bs;
#pragma unroll
                for (int ss = 0; ss < 16; ++ss) sum += partb[ss * 34 + tid];
                float act = ((tid >> 3) == 2) ? tanh_fast(sum) : sigf(sum);
                const int e = tid & 7;
                float vi = __shfl(act, e, 64);
                float vf = __shfl(act, e + 8, 64);
                float vg = __shfl(act, e + 16, 64);
                float vo = __shfl(act, e + 24, 64);
                if (tid < 8) {
                    float c = vf * cstate + vi * vg;
                    cstate = c;
                    float h = vo * tanh_fast(c);
                    astore64(h2pub + (size_t)t * 256 + jb + tid,
                             ((u64)(t + 1) << 32) | (u64)__float_as_uint(h));
                    h2seq[(size_t)t * 256 + jb + tid] = lrelu(h);
                }
            }
        }
    }
}

// ---------------- GCN edge scatter: y[dst] += ew * m[src] ----------------------
__global__ void gcn_scatter(const float* __restrict__ m, const int* __restrict__ ei,
                            const float* __restrict__ ew, float* __restrict__ y,
                            int shift, int nE)
{
    int idx = blockIdx.x * 256 + threadIdx.x;
    int e = idx >> shift;
    if (e >= nE) return;
    int C = 1 << shift;
    int ch = idx & (C - 1);
    int s = ei[e], d = ei[nE + e];
    atomicAdd(&y[(size_t)d * C + ch], ew[e] * m[(size_t)s * C + ch]);
}

// ---------------- BN (training-mode batch stats) -------------------------------
__global__ __launch_bounds__(256) void bn_stats(
    const float* __restrict__ x, const float* __restrict__ gamma,
    const float* __restrict__ beta, float* __restrict__ scale,
    float* __restrict__ shift, int Nn, int C)
{
    int ch = blockIdx.x;
    float s = 0.f, s2 = 0.f;
    for (int n = threadIdx.x; n < Nn; n += 256) {
        float v = x[(size_t)n * C + ch];
        s += v; s2 += v * v;
    }
    __shared__ float rs[256], rq[256];
    rs[threadIdx.x] = s; rq[threadIdx.x] = s2;
    __syncthreads();
    for (int o = 128; o > 0; o >>= 1) {
        if (threadIdx.x < o) {
            rs[threadIdx.x] += rs[threadIdx.x + o];
            rq[threadIdx.x] += rq[threadIdx.x + o];
        }
        __syncthreads();
    }
    if (threadIdx.x == 0) {
        float mean = rs[0] / Nn;
        float var = rq[0] / Nn - mean * mean;
        float inv = rsqrtf(var + 1e-5f);
        float sc = gamma[ch] * inv;
        scale[ch] = sc;
        shift[ch] = beta[ch] - mean * sc;
    }
}

__global__ void bn_apply(const float* __restrict__ x, const float* __restrict__ scale,
                         const float* __restrict__ shift, float* __restrict__ z,
                         int mask, int total)
{
    int idx = blockIdx.x * 256 + threadIdx.x;
    if (idx >= total) return;
    int ch = idx & mask;
    z[idx] = lrelu(x[idx] * scale[ch] + shift[ch]);
}

// ---------------- global_add_pool via batch array ------------------------------
__global__ void pool_kernel(const float* __restrict__ z, const int* __restrict__ batch,
                            float* __restrict__ pooled, int total)
{
    int idx = blockIdx.x * 256 + threadIdx.x;
    if (idx >= total) return;
    int n = idx >> 5, ch = idx & 31;
    atomicAdd(&pooled[(size_t)batch[n] * 32 + ch], z[idx]);
}

// ---------------- final tiny MLP: 32 -> 16 -> 8 -> 2, one thread per graph -----
__global__ void mlp_kernel(const float* __restrict__ pooled,
                           const float* __restrict__ w2, const float* __restrict__ b2,
                           const float* __restrict__ w3, const float* __restrict__ b3,
                           const float* __restrict__ w4, const float* __restrict__ b4,
                           float* __restrict__ out)
{
    int g = blockIdx.x * 256 + threadIdx.x;
    if (g >= 512) return;
    float pbuf[32];
#pragma unroll
    for (int i = 0; i < 32; i++) pbuf[i] = pooled[g * 32 + i];
    float a[16];
#pragma unroll
    for (int j = 0; j < 16; j++) {
        float s = b2[j];
#pragma unroll
        for (int i = 0; i < 32; i++) s += w2[j * 32 + i] * pbuf[i];
        a[j] = lrelu(s);
    }
    float c8[8];
#pragma unroll
    for (int j = 0; j < 8; j++) {
        float s = b3[j];
#pragma unroll
        for (int i = 0; i < 16; i++) s += w3[j * 16 + i] * a[i];
        c8[j] = lrelu(s);
    }
#pragma unroll
    for (int j = 0; j < 2; j++) {
        float s = b4[j];
#pragma unroll
        for (int i = 0; i < 8; i++) s += w4[j * 8 + i] * c8[i];
        out[g * 2 + j] = lrelu(s);
    }
}

extern "C" void kernel_launch(void* const* d_in, const int* in_sizes, int n_in,
                              void* d_out, int out_size, void* d_ws, size_t ws_size,
                              hipStream_t stream)
{
    (void)in_sizes; (void)n_in; (void)out_size; (void)ws_size;
    const float* x      = (const float*)d_in[0];
    const int*   ei     = (const int*)d_in[1];
    const float* ew     = (const float*)d_in[2];
    const int*   batch  = (const int*)d_in[3];
    const float* W_ih1  = (const float*)d_in[4];
    const float* W_hh1  = (const float*)d_in[5];
    const float* b_ih1  = (const float*)d_in[6];
    const float* b_hh1  = (const float*)d_in[7];
    const float* W_ih2  = (const float*)d_in[8];
    const float* W_hh2  = (const float*)d_in[9];
    const float* b_ih2  = (const float*)d_in[10];
    const float* b_hh2  = (const float*)d_in[11];
    const float* fc1_w  = (const float*)d_in[12];
    const float* fc1_b  = (const float*)d_in[13];
    const float* gcn1_w = (const float*)d_in[14];
    const float* bn1_g  = (const float*)d_in[16];
    const float* bn1_b  = (const float*)d_in[17];
    const float* gcn2_w = (const float*)d_in[18];
    const float* bn2_g  = (const float*)d_in[20];
    const float* bn2_b  = (const float*)d_in[21];
    const float* fc2_w  = (const float*)d_in[22];
    const float* fc2_b  = (const float*)d_in[23];
    const float* fc3_w  = (const float*)d_in[24];
    const float* fc3_b  = (const float*)d_in[25];
    const float* fc4_w  = (const float*)d_in[26];
    const float* fc4_b  = (const float*)d_in[27];
    float* out = (float*)d_out;

    // -------- workspace layout --------
    float* ws    = (float*)d_ws;
    float* gx1   = ws;                                   // 4096*2048 f32 (32MB)
    u64*   h1pub = (u64*)(gx1 + (size_t)4096 * 2048);    // 4096*512 u64 (16MB)
    u64*   h2pub = h1pub + (size_t)4096 * 512;           // 4096*256 u64 (8MB)
    float* h2seq = (float*)(h2pub + (size_t)4096 * 256); // 4096*256 f32 (4MB)
    float* scale1 = h2seq + (size_t)4096 * 256;          // 64
    float* shift1 = scale1 + 64;                         // 64
    float* scale2 = shift1 + 64;                         // 32
    float* shift2 = scale2 + 32;                         // 32
    // buffers used only AFTER lstm_pipe — aliased into gx1's space:
    float* h3    = ws;                                   // 4096*128
    float* m1    = h3 + (size_t)4096 * 128;              // 4096*64
    float* y1    = m1 + (size_t)4096 * 64;               // 4096*64 (bn in-place)
    float* m2    = y1 + (size_t)4096 * 64;               // 4096*32
    float* y2    = m2 + (size_t)4096 * 32;               // 4096*32 (bn in-place)
    float* pooled = y2 + (size_t)4096 * 32;              // 512*32

    dim3 b256(256);

    // fresh tags every launch (no cross-call state)
    hipMemsetAsync(h1pub, 0, (size_t)4096 * 768 * sizeof(u64), stream);

    // gx1 = x @ W_ih1^T + (b_ih1 + b_hh1)   [4096,2048]
    gemm_bias<false><<<dim3(2048 / 64, 4096 / 64), b256, 0, stream>>>(
        x, W_ih1, b_ih1, b_hh1, gx1, 4096, 2048, 1280);

    // both LSTM scans, pipelined (persistent, 96 WGs)
    lstm_pipe<<<96, b256, 0, stream>>>(gx1, W_hh1, W_ih2, W_hh2, b_ih2, b_hh2,
                                       h1pub, h2pub, h2seq);

    // fc1 + lrelu  [4096,128]
    gemm_bias<true><<<dim3(128 / 64, 4096 / 64), b256, 0, stream>>>(
        h2seq, fc1_w, fc1_b, nullptr, h3, 4096, 128, 256);

    // gcn1 linear [4096,64]  (bias cancels in BN)
    gemm_bias<false><<<dim3(1, 4096 / 64), b256, 0, stream>>>(
        h3, gcn1_w, nullptr, nullptr, m1, 4096, 64, 128);
    hipMemsetAsync(y1, 0, (size_t)4096 * 64 * sizeof(float), stream);
    gcn_scatter<<<(32768 * 64) / 256, b256, 0, stream>>>(m1, ei, ew, y1, 6, 32768);
    bn_stats<<<64, b256, 0, stream>>>(y1, bn1_g, bn1_b, scale1, shift1, 4096, 64);
    bn_apply<<<(4096 * 64) / 256, b256, 0, stream>>>(y1, scale1, shift1, y1, 63, 4096 * 64);

    // gcn2 linear [4096,32]
    gemm_bias<false><<<dim3(1, 4096 / 64), b256, 0, stream>>>(
        y1, gcn2_w, nullptr, nullptr, m2, 4096, 32, 64);
    hipMemsetAsync(y2, 0, (size_t)4096 * 32 * sizeof(float), stream);
    gcn_scatter<<<(32768 * 32) / 256, b256, 0, stream>>>(m2, ei, ew, y2, 5, 32768);
    bn_stats<<<32, b256, 0, stream>>>(y2, bn2_g, bn2_b, scale2, shift2, 4096, 32);
    bn_apply<<<(4096 * 32) / 256, b256, 0, stream>>>(y2, scale2, shift2, y2, 31, 4096 * 32);

    // pool + MLP head
    hipMemsetAsync(pooled, 0, (size_t)512 * 32 * sizeof(float), stream);
    pool_kernel<<<(4096 * 32) / 256, b256, 0, stream>>>(y2, batch, pooled, 4096 * 32);
    mlp_kernel<<<2, b256, 0, stream>>>(pooled, fc2_w, fc2_b, fc3_w, fc3_b,
                                       fc4_w, fc4_b, out);
}